// Round 10
// baseline (648.195 us; speedup 1.0000x reference)
//
#include <hip/hip_runtime.h>
#include <hip/hip_bf16.h>
#include <math.h>

typedef __attribute__((ext_vector_type(8))) short bf16x8;
typedef __attribute__((ext_vector_type(4))) float f32x4;

#define FRAME_PAD (66*66*128)   // padded NHWC frame elems (557568)

#define GLOAD_LDS16(g, l) \
    __builtin_amdgcn_global_load_lds((const __attribute__((address_space(1))) void*)(g), \
                                     (__attribute__((address_space(3))) void*)(l), 16, 0, 0)

#define WAITV4    asm volatile("s_waitcnt vmcnt(4)" ::: "memory")
#define WAITV0    asm volatile("s_waitcnt vmcnt(0)" ::: "memory")
#define WAITLGKM0 asm volatile("s_waitcnt lgkmcnt(0)" ::: "memory")
#define SBAR      __builtin_amdgcn_s_barrier()

__device__ __forceinline__ float sigmoidf_(float x) { return 1.0f / (1.0f + __expf(-x)); }
__device__ __forceinline__ float tanhf_(float x) {
    x = fminf(fmaxf(x, -15.0f), 15.0f);
    float e = __expf(2.0f * x);
    return (e - 1.0f) / (e + 1.0f);
}
__device__ __forceinline__ float b2f_(short u) {
    unsigned int v = ((unsigned int)(unsigned short)u) << 16;
    return __builtin_bit_cast(float, v);
}
__device__ __forceinline__ short f2b_(float f) {
    __hip_bfloat16 hb = __float2bfloat16(f);
    return *reinterpret_cast<short*>(&hb);
}

// ---------- weights: W[oc][ic][tap] f32 -> Wt[tap][n'][ic] bf16, n' = c*4 + gate ----------
__global__ void wt_kernel(const float* __restrict__ w, __hip_bfloat16* __restrict__ wt)
{
    int idx = blockIdx.x * 256 + threadIdx.x;       // tap*131072 + n*256 + ic
    if (idx >= 9 * 512 * 256) return;
    int ic  = idx & 255;
    int n   = (idx >> 8) & 511;
    int tap = idx >> 17;
    int c = n >> 2, g = n & 3;                       // gate 0:i 1:f 2:o 3:g
    int oc = g * 128 + c;
    wt[idx] = __float2bfloat16(w[((size_t)oc * 256 + (size_t)ic) * 9 + tap]);
}

// ---------- zero the pad borders of all x and h frames ----------
__global__ void border_kernel(__hip_bfloat16* __restrict__ x_pad,
                              __hip_bfloat16* __restrict__ h_pad)
{
    const int fr = blockIdx.x;                        // 0..31 x, 32..63 h
    __hip_bfloat16* base = (fr < 32) ? x_pad + (size_t)fr * FRAME_PAD
                                     : h_pad + (size_t)(fr - 32) * FRAME_PAD;
    bf16x8 z = {};
    for (int u = threadIdx.x; u < 2112; u += 256) {
        int half = (u >= 1056) ? 1 : 0;
        int v = u - half * 1056;
        *(bf16x8*)(base + (size_t)(half * 65 * 66) * 128 + (size_t)v * 8) = z;
    }
    for (int u = threadIdx.x; u < 2048; u += 256) {
        int yy = 1 + (u >> 5);
        int r = u & 31;
        int side = r >> 4, c16 = r & 15;
        *(bf16x8*)(base + (size_t)(yy * 66 + side * 65) * 128 + (size_t)c16 * 8) = z;
    }
}

// ---------- x: NCHW f32 -> padded NHWC bf16 (vectorized, LDS stride-129 transpose) ----------
__global__ void xpose_kernel(const float* __restrict__ x, __hip_bfloat16* __restrict__ x_pad)
{
    __shared__ float tile[64][129];                  // [x][c]
    const int f = blockIdx.x >> 6;
    const int y = blockIdx.x & 63;
    const int tid = threadIdx.x;
    const float* src = x + (size_t)f * 524288 + (size_t)y * 64;
    #pragma unroll
    for (int it = 0; it < 8; ++it) {
        int c  = it * 16 + (tid >> 4);
        int xq = tid & 15;
        float4 v = *(const float4*)(src + (size_t)c * 4096 + xq * 4);
        tile[xq * 4 + 0][c] = v.x;
        tile[xq * 4 + 1][c] = v.y;
        tile[xq * 4 + 2][c] = v.z;
        tile[xq * 4 + 3][c] = v.w;
    }
    __syncthreads();
    __hip_bfloat16* dst = x_pad + (size_t)f * FRAME_PAD + (size_t)((y + 1) * 66 + 1) * 128;
    const int g = tid & 15;
    #pragma unroll
    for (int it = 0; it < 4; ++it) {
        int xr = it * 16 + (tid >> 4);
        bf16x8 o;
        #pragma unroll
        for (int e = 0; e < 8; ++e) o[e] = f2b_(tile[xr][g * 8 + e]);
        *(bf16x8*)(dst + (size_t)xr * 128 + g * 8) = o;
    }
}

// ---------- fused conv-GEMM + LSTM + BN/ReLU; W-operands direct from L2 to registers ----------
// D[n'][m]: n' (512, BN=128), m (16384, BM=128), BK=64. LDS holds ONLY the A (spatial)
// dbuf (32KB) -> LDS reads halved vs W-in-LDS (8 ds_read_b128/wave/K-tile); MFMA becomes
// the binding resource. W-frags: per-lane 16B global loads (L2-resident 2.25MB panel),
// double-buffered in named reg sets wA/wB, issued one K-tile ahead.
// vmcnt ledger (per-thread FIFO): [A(kt):4][W(kt):8][A(kt+1):4] at top-of-iter ->
// vmcnt(4) retires A(kt)+W(kt), keeps A(kt+1) in flight; iter issues W(kt+1) at top,
// A(kt+2) after the mid-barrier (order preserved by "memory"-clobber asm between).
template<bool T0>
__global__ __launch_bounds__(256, 2)
void conv_gemm(const __hip_bfloat16* __restrict__ x_pad,
               const __hip_bfloat16* __restrict__ h_pad,
               const __hip_bfloat16* __restrict__ wt,
               const float* __restrict__ bias,
               const float* __restrict__ gamma, const float* __restrict__ beta,
               const float* __restrict__ rmean, const float* __restrict__ rvar,
               float* __restrict__ c_state, float* __restrict__ out, int t)
{
    __shared__ alignas(16) __hip_bfloat16 S_s[2][128 * 64];   // spatial dbuf, 2x16KB
    const int tid  = threadIdx.x;
    const int wv   = tid >> 6;
    const int lane = tid & 63;
    const int KT   = T0 ? 18 : 36;

    // XCD-chunked remap: each XCD owns 64 consecutive tiles (16 m-panels x 4 n-blocks).
    const int F    = blockIdx.x;                 // 512 blocks
    const int tile = (F >> 3) + (F & 7) * 64;
    const int n0   = (tile & 3) * 128;
    const int mblk = tile >> 2;                  // 0..127
    const int b    = mblk >> 5;
    const int y0   = (mblk & 31) * 2;
    const int m0   = mblk * 128;

    const __hip_bfloat16* xf = x_pad + (size_t)(b * 8 + t) * FRAME_PAD;
    const __hip_bfloat16* hf = T0 ? xf
                                  : h_pad + (size_t)(b * 8 + t - 1) * FRAME_PAD;

    // A staging offsets (source pre-swizzled: q_src = q ^ (row&7), involution)
    int aOff[4];
    #pragma unroll
    for (int j = 0; j < 4; ++j) {
        int sid = j * 256 + tid;
        int row = sid >> 3;
        int q   = (sid & 7) ^ (row & 7);
        aOff[j] = ((y0 + (row >> 6)) * 66 + (row & 63)) * 128 + q * 8;
    }

    auto STAGE_A = [&](__hip_bfloat16* Sl, int kt) {
        int tap, icq;
        const __hip_bfloat16* sb;
        if constexpr (T0) { tap = kt >> 1; icq = (kt & 1) * 64; sb = xf + icq; }
        else { tap = kt >> 2; icq = (kt & 3) * 64;
               sb = (icq < 128) ? (xf + icq) : (hf + (icq - 128)); }
        const int dy = tap / 3, dx = tap % 3;
        const __hip_bfloat16* a = sb + (dy * 66 + dx) * 128;
        #pragma unroll
        for (int j = 0; j < 4; ++j)
            GLOAD_LDS16(a + aOff[j], Sl + (size_t)(j * 256 + tid) * 8);
    };

    const int wm = wv >> 1, wn = wv & 1;
    const int fr = lane & 15, fq = lane >> 4;

    // W lane base: row n' = n0 + wn*64 + ri*16 + fr, k = icq + fq*8 (+32 for K-half1)
    const __hip_bfloat16* wlane = wt + (size_t)(n0 + wn * 64 + fr) * 256 + fq * 8;
    auto LOADW = [&](bf16x8* wreg, int kt) {     // wreg[0..3]=half0 ri, [4..7]=half1 ri
        int tap, icq;
        if constexpr (T0) { tap = kt >> 1; icq = (kt & 1) * 64; }
        else { tap = kt >> 2; icq = (kt & 3) * 64; }
        const __hip_bfloat16* p = wlane + (size_t)tap * 131072 + icq;
        #pragma unroll
        for (int ri = 0; ri < 4; ++ri) {
            wreg[ri]     = *(const bf16x8*)(p + ri * 4096);
            wreg[4 + ri] = *(const bf16x8*)(p + ri * 4096 + 32);
        }
    };

    // A fragment read offsets (swizzled, lane-constant); K-half1 = XOR 32 elems (64B)
    const int slot = (fq ^ (fr & 7)) * 8;
    const int sOff0 = (wm * 64 + fr) * 64 + slot, sOff1 = sOff0 ^ 32;

    f32x4 acc[4][4] = {};
    bf16x8 wA[8], wB[8];

    auto ITER = [&](__hip_bfloat16* Sb, bf16x8* wuse, bf16x8* wload, int kt) {
        if (kt < KT - 1) { WAITV4; } else { WAITV0; }   // A(kt)+W(kt) landed
        SBAR;
        if (kt < KT - 1) LOADW(wload, kt + 1);          // W(kt+1) issued before A(kt+2)
        bf16x8 s0[4], s1[4];
        #pragma unroll
        for (int ci = 0; ci < 4; ++ci) {
            s0[ci] = *(const bf16x8*)(Sb + sOff0 + ci * 1024);
            s1[ci] = *(const bf16x8*)(Sb + sOff1 + ci * 1024);
        }
        __builtin_amdgcn_s_setprio(1);
        #pragma unroll
        for (int ri = 0; ri < 4; ++ri)
            #pragma unroll
            for (int ci = 0; ci < 4; ++ci)
                acc[ri][ci] = __builtin_amdgcn_mfma_f32_16x16x32_bf16(wuse[ri], s0[ci], acc[ri][ci], 0, 0, 0);
        __builtin_amdgcn_s_setprio(0);
        WAITLGKM0;                               // all 8 A-reads hardware-complete
        __builtin_amdgcn_sched_barrier(0);       // rule 18: pin the boundary
        SBAR;                                    // all waves done reading this A buffer
        if (kt < KT - 2) STAGE_A(Sb, kt + 2);    // overwrite now safe; loads fly ahead
        __builtin_amdgcn_s_setprio(1);
        #pragma unroll
        for (int ri = 0; ri < 4; ++ri)
            #pragma unroll
            for (int ci = 0; ci < 4; ++ci)
                acc[ri][ci] = __builtin_amdgcn_mfma_f32_16x16x32_bf16(wuse[4 + ri], s1[ci], acc[ri][ci], 0, 0, 0);
        __builtin_amdgcn_s_setprio(0);
    };

    STAGE_A(S_s[0], 0);                          // FIFO: [A0:4]
    LOADW(wA, 0);                                // [A0:4, W0:8]
    STAGE_A(S_s[1], 1);                          // [A0:4, W0:8, A1:4]
    #pragma unroll 1
    for (int kt = 0; kt < KT; kt += 2) {
        ITER(S_s[0], wA, wB, kt);
        ITER(S_s[1], wB, wA, kt + 1);
    }

    // ---------- fused LSTM gates + BN(eval)+ReLU output epilogue ----------
    const int c0    = (n0 >> 2) + wn * 16;
    const int mcol0 = m0 + wm * 64 + fr;
    __hip_bfloat16* hout = (__hip_bfloat16*)h_pad + (size_t)(b * 8 + t) * FRAME_PAD;
    float* oframe = out + (size_t)(b * 8 + t) * 524288;
    #pragma unroll
    for (int ri = 0; ri < 4; ++ri) {
        const int c = c0 + ri * 4 + fq;
        const float bi  = bias[c];
        const float bfv = bias[128 + c];
        const float bo  = bias[256 + c];
        const float bg  = bias[384 + c];
        const float scv = gamma[c] * rsqrtf(rvar[c] + 1e-5f);
        const float shv = beta[c] - rmean[c] * scv;
        float* csrow = c_state + (size_t)c * 16384;
        #pragma unroll
        for (int ci = 0; ci < 4; ++ci) {
            const int m = mcol0 + ci * 16;
            const int s = m & 4095;
            const float cold = T0 ? 0.0f : csrow[m];
            const float zi = acc[ri][ci][0] + bi;
            const float zf = acc[ri][ci][1] + bfv;
            const float zo = acc[ri][ci][2] + bo;
            const float zg = acc[ri][ci][3] + bg;
            const float cn = sigmoidf_(zf) * cold + sigmoidf_(zi) * tanhf_(zg);
            const float h  = sigmoidf_(zo) * tanhf_(cn);
            csrow[m] = cn;
            hout[(size_t)(((s >> 6) + 1) * 66 + (s & 63) + 1) * 128 + c] = __float2bfloat16(h);
            oframe[(size_t)c * 4096 + s] = fmaxf(h * scv + shv, 0.0f);
        }
    }
}

extern "C" void kernel_launch(void* const* d_in, const int* in_sizes, int n_in,
                              void* d_out, int out_size, void* d_ws, size_t ws_size,
                              hipStream_t stream)
{
    const float* x      = (const float*)d_in[0];
    const float* w_conv = (const float*)d_in[1];
    const float* b_conv = (const float*)d_in[2];
    const float* gamma  = (const float*)d_in[3];
    const float* beta   = (const float*)d_in[4];
    const float* rmean  = (const float*)d_in[5];
    const float* rvar   = (const float*)d_in[6];
    float* out = (float*)d_out;

    // workspace layout (bytes)
    //   Wt      @ 0          : 9*512*256*2    = 2,359,296
    //   x_pad   @ 2359296    : 32*66*66*128*2 = 35,684,352
    //   h_pad   @ 38043648   : 32*66*66*128*2 = 35,684,352   (slot b*8+t = h after step t)
    //   c_state @ 73728000   : 128*16384*4    = 8,388,608    ([c][m]; written before read)
    //   total 82,116,608
    if (ws_size < 82116608u) return;

    char* ws = (char*)d_ws;
    __hip_bfloat16* Wt    = (__hip_bfloat16*)(ws);
    __hip_bfloat16* x_pad = (__hip_bfloat16*)(ws + 2359296);
    __hip_bfloat16* h_pad = (__hip_bfloat16*)(ws + 38043648);
    float* c_state        = (float*)(ws + 73728000);

    wt_kernel<<<4608, 256, 0, stream>>>(w_conv, Wt);
    xpose_kernel<<<2048, 256, 0, stream>>>(x, x_pad);
    border_kernel<<<64, 256, 0, stream>>>(x_pad, h_pad);

    conv_gemm<true><<<512, 256, 0, stream>>>(x_pad, h_pad, Wt, b_conv,
                                             gamma, beta, rmean, rvar, c_state, out, 0);
    for (int t = 1; t < 8; ++t)
        conv_gemm<false><<<512, 256, 0, stream>>>(x_pad, h_pad, Wt, b_conv,
                                                  gamma, beta, rmean, rvar, c_state, out, t);
}

// Round 11
// 646.847 us; speedup vs baseline: 1.0021x; 1.0021x over previous
//
#include <hip/hip_runtime.h>
#include <hip/hip_bf16.h>
#include <math.h>

typedef __attribute__((ext_vector_type(8))) short bf16x8;
typedef __attribute__((ext_vector_type(4))) float f32x4;

#define FRAME_PAD (66*66*128)   // padded NHWC frame elems (557568)

#define GLOAD_LDS16(g, l) \
    __builtin_amdgcn_global_load_lds((const __attribute__((address_space(1))) void*)(g), \
                                     (__attribute__((address_space(3))) void*)(l), 16, 0, 0)

#define WAITV4    asm volatile("s_waitcnt vmcnt(4)" ::: "memory")
#define WAITV0    asm volatile("s_waitcnt vmcnt(0)" ::: "memory")
#define WAITLGKM0 asm volatile("s_waitcnt lgkmcnt(0)" ::: "memory")
#define SBAR      __builtin_amdgcn_s_barrier()

__device__ __forceinline__ float sigmoidf_(float x) { return 1.0f / (1.0f + __expf(-x)); }
__device__ __forceinline__ float tanhf_(float x) {
    x = fminf(fmaxf(x, -15.0f), 15.0f);
    float e = __expf(2.0f * x);
    return (e - 1.0f) / (e + 1.0f);
}
__device__ __forceinline__ float b2f_(short u) {
    unsigned int v = ((unsigned int)(unsigned short)u) << 16;
    return __builtin_bit_cast(float, v);
}
__device__ __forceinline__ short f2b_(float f) {
    __hip_bfloat16 hb = __float2bfloat16(f);
    return *reinterpret_cast<short*>(&hb);
}

// ---------- weights: W[oc][ic][tap] f32 -> Wt[tap][n'][ic] bf16, n' = c*4 + gate ----------
__global__ void wt_kernel(const float* __restrict__ w, __hip_bfloat16* __restrict__ wt)
{
    int idx = blockIdx.x * 256 + threadIdx.x;       // tap*131072 + n*256 + ic
    if (idx >= 9 * 512 * 256) return;
    int ic  = idx & 255;
    int n   = (idx >> 8) & 511;
    int tap = idx >> 17;
    int c = n >> 2, g = n & 3;                       // gate 0:i 1:f 2:o 3:g
    int oc = g * 128 + c;
    wt[idx] = __float2bfloat16(w[((size_t)oc * 256 + (size_t)ic) * 9 + tap]);
}

// ---------- zero the pad borders of all x and h frames ----------
__global__ void border_kernel(__hip_bfloat16* __restrict__ x_pad,
                              __hip_bfloat16* __restrict__ h_pad)
{
    const int fr = blockIdx.x;                        // 0..31 x, 32..63 h
    __hip_bfloat16* base = (fr < 32) ? x_pad + (size_t)fr * FRAME_PAD
                                     : h_pad + (size_t)(fr - 32) * FRAME_PAD;
    bf16x8 z = {};
    for (int u = threadIdx.x; u < 2112; u += 256) {
        int half = (u >= 1056) ? 1 : 0;
        int v = u - half * 1056;
        *(bf16x8*)(base + (size_t)(half * 65 * 66) * 128 + (size_t)v * 8) = z;
    }
    for (int u = threadIdx.x; u < 2048; u += 256) {
        int yy = 1 + (u >> 5);
        int r = u & 31;
        int side = r >> 4, c16 = r & 15;
        *(bf16x8*)(base + (size_t)(yy * 66 + side * 65) * 128 + (size_t)c16 * 8) = z;
    }
}

// ---------- x: NCHW f32 -> padded NHWC bf16 (vectorized, LDS stride-129 transpose) ----------
__global__ void xpose_kernel(const float* __restrict__ x, __hip_bfloat16* __restrict__ x_pad)
{
    __shared__ float tile[64][129];                  // [x][c]
    const int f = blockIdx.x >> 6;
    const int y = blockIdx.x & 63;
    const int tid = threadIdx.x;
    const float* src = x + (size_t)f * 524288 + (size_t)y * 64;
    #pragma unroll
    for (int it = 0; it < 8; ++it) {
        int c  = it * 16 + (tid >> 4);
        int xq = tid & 15;
        float4 v = *(const float4*)(src + (size_t)c * 4096 + xq * 4);
        tile[xq * 4 + 0][c] = v.x;
        tile[xq * 4 + 1][c] = v.y;
        tile[xq * 4 + 2][c] = v.z;
        tile[xq * 4 + 3][c] = v.w;
    }
    __syncthreads();
    __hip_bfloat16* dst = x_pad + (size_t)f * FRAME_PAD + (size_t)((y + 1) * 66 + 1) * 128;
    const int g = tid & 15;
    #pragma unroll
    for (int it = 0; it < 4; ++it) {
        int xr = it * 16 + (tid >> 4);
        bf16x8 o;
        #pragma unroll
        for (int e = 0; e < 8; ++e) o[e] = f2b_(tile[xr][g * 8 + e]);
        *(bf16x8*)(dst + (size_t)xr * 128 + g * 8) = o;
    }
}

// ---------- fused conv-GEMM + LSTM + BN/ReLU; W direct L2->NAMED registers ----------
// Same plan as R10 but W lives in 16 individually NAMED bf16x8 registers (scratch-proof,
// rule #20: R10's lambda-pointer arrays demoted to scratch -> VGPR=104 + 2x slowdown).
// LDS holds only the A dbuf (32KB) -> 8 ds_read_b128/wave/K-tile; MFMA is the binding
// resource. vmcnt FIFO ledger: [A(kt):4][W(kt):8][A(kt+1):4] -> WAITV4 retires A+W(kt).
#define MF(d, wreg, sreg) d = __builtin_amdgcn_mfma_f32_16x16x32_bf16(wreg, sreg, d, 0, 0, 0)

#define LOADW(SET, ktv) do {                                             \
    int tap_, icq_;                                                      \
    if (T0) { tap_ = (ktv) >> 1; icq_ = ((ktv) & 1) * 64; }              \
    else    { tap_ = (ktv) >> 2; icq_ = ((ktv) & 3) * 64; }              \
    const __hip_bfloat16* p_ = wlane + (size_t)tap_ * 131072 + icq_;     \
    SET##0 = *(const bf16x8*)(p_ + 0 * 4096);                            \
    SET##4 = *(const bf16x8*)(p_ + 0 * 4096 + 32);                       \
    SET##1 = *(const bf16x8*)(p_ + 1 * 4096);                            \
    SET##5 = *(const bf16x8*)(p_ + 1 * 4096 + 32);                       \
    SET##2 = *(const bf16x8*)(p_ + 2 * 4096);                            \
    SET##6 = *(const bf16x8*)(p_ + 2 * 4096 + 32);                       \
    SET##3 = *(const bf16x8*)(p_ + 3 * 4096);                            \
    SET##7 = *(const bf16x8*)(p_ + 3 * 4096 + 32);                       \
} while (0)

#define ITER(Sb, WU, WL, ktv) do {                                       \
    if ((ktv) < KT - 1) { WAITV4; } else { WAITV0; }                     \
    SBAR;                                                                \
    if ((ktv) < KT - 1) LOADW(WL, (ktv) + 1);                            \
    bf16x8 s00 = *(const bf16x8*)((Sb) + sOff0 + 0 * 1024);              \
    bf16x8 s01 = *(const bf16x8*)((Sb) + sOff0 + 1 * 1024);              \
    bf16x8 s02 = *(const bf16x8*)((Sb) + sOff0 + 2 * 1024);              \
    bf16x8 s03 = *(const bf16x8*)((Sb) + sOff0 + 3 * 1024);              \
    bf16x8 s10 = *(const bf16x8*)((Sb) + sOff1 + 0 * 1024);              \
    bf16x8 s11 = *(const bf16x8*)((Sb) + sOff1 + 1 * 1024);              \
    bf16x8 s12 = *(const bf16x8*)((Sb) + sOff1 + 2 * 1024);              \
    bf16x8 s13 = *(const bf16x8*)((Sb) + sOff1 + 3 * 1024);              \
    __builtin_amdgcn_s_setprio(1);                                       \
    MF(acc[0][0], WU##0, s00); MF(acc[0][1], WU##0, s01);                \
    MF(acc[0][2], WU##0, s02); MF(acc[0][3], WU##0, s03);                \
    MF(acc[1][0], WU##1, s00); MF(acc[1][1], WU##1, s01);                \
    MF(acc[1][2], WU##1, s02); MF(acc[1][3], WU##1, s03);                \
    MF(acc[2][0], WU##2, s00); MF(acc[2][1], WU##2, s01);                \
    MF(acc[2][2], WU##2, s02); MF(acc[2][3], WU##2, s03);                \
    MF(acc[3][0], WU##3, s00); MF(acc[3][1], WU##3, s01);                \
    MF(acc[3][2], WU##3, s02); MF(acc[3][3], WU##3, s03);                \
    __builtin_amdgcn_s_setprio(0);                                       \
    WAITLGKM0;                                                           \
    __builtin_amdgcn_sched_barrier(0);                                   \
    SBAR;                                                                \
    if ((ktv) < KT - 2) STAGE_A(Sb, (ktv) + 2);                          \
    __builtin_amdgcn_s_setprio(1);                                       \
    MF(acc[0][0], WU##4, s10); MF(acc[0][1], WU##4, s11);                \
    MF(acc[0][2], WU##4, s12); MF(acc[0][3], WU##4, s13);                \
    MF(acc[1][0], WU##5, s10); MF(acc[1][1], WU##5, s11);                \
    MF(acc[1][2], WU##5, s12); MF(acc[1][3], WU##5, s13);                \
    MF(acc[2][0], WU##6, s10); MF(acc[2][1], WU##6, s11);                \
    MF(acc[2][2], WU##6, s12); MF(acc[2][3], WU##6, s13);                \
    MF(acc[3][0], WU##7, s10); MF(acc[3][1], WU##7, s11);                \
    MF(acc[3][2], WU##7, s12); MF(acc[3][3], WU##7, s13);                \
    __builtin_amdgcn_s_setprio(0);                                       \
} while (0)

template<bool T0>
__global__ __launch_bounds__(256, 2)
void conv_gemm(const __hip_bfloat16* __restrict__ x_pad,
               const __hip_bfloat16* __restrict__ h_pad,
               const __hip_bfloat16* __restrict__ wt,
               const float* __restrict__ bias,
               const float* __restrict__ gamma, const float* __restrict__ beta,
               const float* __restrict__ rmean, const float* __restrict__ rvar,
               float* __restrict__ c_state, float* __restrict__ out, int t)
{
    __shared__ alignas(16) __hip_bfloat16 S_s[2][128 * 64];   // spatial dbuf, 2x16KB
    const int tid  = threadIdx.x;
    const int wv   = tid >> 6;
    const int lane = tid & 63;
    const int KT   = T0 ? 18 : 36;

    // XCD-chunked remap: each XCD owns 64 consecutive tiles (16 m-panels x 4 n-blocks).
    const int F    = blockIdx.x;                 // 512 blocks
    const int tile = (F >> 3) + (F & 7) * 64;
    const int n0   = (tile & 3) * 128;
    const int mblk = tile >> 2;                  // 0..127
    const int b    = mblk >> 5;
    const int y0   = (mblk & 31) * 2;
    const int m0   = mblk * 128;

    const __hip_bfloat16* xf = x_pad + (size_t)(b * 8 + t) * FRAME_PAD;
    const __hip_bfloat16* hf = T0 ? xf
                                  : h_pad + (size_t)(b * 8 + t - 1) * FRAME_PAD;

    // A staging offsets (source pre-swizzled: q_src = q ^ (row&7), involution)
    int aOff[4];
    #pragma unroll
    for (int j = 0; j < 4; ++j) {
        int sid = j * 256 + tid;
        int row = sid >> 3;
        int q   = (sid & 7) ^ (row & 7);
        aOff[j] = ((y0 + (row >> 6)) * 66 + (row & 63)) * 128 + q * 8;
    }

    auto STAGE_A = [&](__hip_bfloat16* Sl, int kt) {
        int tap, icq;
        const __hip_bfloat16* sb;
        if constexpr (T0) { tap = kt >> 1; icq = (kt & 1) * 64; sb = xf + icq; }
        else { tap = kt >> 2; icq = (kt & 3) * 64;
               sb = (icq < 128) ? (xf + icq) : (hf + (icq - 128)); }
        const int dy = tap / 3, dx = tap % 3;
        const __hip_bfloat16* a = sb + (dy * 66 + dx) * 128;
        #pragma unroll
        for (int j = 0; j < 4; ++j)
            GLOAD_LDS16(a + aOff[j], Sl + (size_t)(j * 256 + tid) * 8);
    };

    const int wm = wv >> 1, wn = wv & 1;
    const int fr = lane & 15, fq = lane >> 4;

    // W lane base: row n' = n0 + wn*64 + ri*16 + fr, k = icq + fq*8 (+32 for K-half1)
    const __hip_bfloat16* wlane = wt + (size_t)(n0 + wn * 64 + fr) * 256 + fq * 8;

    // A fragment read offsets (swizzled, lane-constant); K-half1 = XOR 32 elems (64B)
    const int slot = (fq ^ (fr & 7)) * 8;
    const int sOff0 = (wm * 64 + fr) * 64 + slot, sOff1 = sOff0 ^ 32;

    f32x4 acc[4][4] = {};
    bf16x8 wA0, wA1, wA2, wA3, wA4, wA5, wA6, wA7;
    bf16x8 wB0, wB1, wB2, wB3, wB4, wB5, wB6, wB7;

    STAGE_A(S_s[0], 0);                          // FIFO: [A0:4]
    LOADW(wA, 0);                                // [A0:4, W0:8]
    STAGE_A(S_s[1], 1);                          // [A0:4, W0:8, A1:4]
    #pragma unroll 1
    for (int kt = 0; kt < KT; kt += 2) {
        ITER(S_s[0], wA, wB, kt);
        ITER(S_s[1], wB, wA, kt + 1);
    }

    // ---------- fused LSTM gates + BN(eval)+ReLU output epilogue ----------
    const int c0    = (n0 >> 2) + wn * 16;
    const int mcol0 = m0 + wm * 64 + fr;
    __hip_bfloat16* hout = (__hip_bfloat16*)h_pad + (size_t)(b * 8 + t) * FRAME_PAD;
    float* oframe = out + (size_t)(b * 8 + t) * 524288;
    #pragma unroll
    for (int ri = 0; ri < 4; ++ri) {
        const int c = c0 + ri * 4 + fq;
        const float bi  = bias[c];
        const float bfv = bias[128 + c];
        const float bo  = bias[256 + c];
        const float bg  = bias[384 + c];
        const float scv = gamma[c] * rsqrtf(rvar[c] + 1e-5f);
        const float shv = beta[c] - rmean[c] * scv;
        float* csrow = c_state + (size_t)c * 16384;
        #pragma unroll
        for (int ci = 0; ci < 4; ++ci) {
            const int m = mcol0 + ci * 16;
            const int s = m & 4095;
            const float cold = T0 ? 0.0f : csrow[m];
            const float zi = acc[ri][ci][0] + bi;
            const float zf = acc[ri][ci][1] + bfv;
            const float zo = acc[ri][ci][2] + bo;
            const float zg = acc[ri][ci][3] + bg;
            const float cn = sigmoidf_(zf) * cold + sigmoidf_(zi) * tanhf_(zg);
            const float h  = sigmoidf_(zo) * tanhf_(cn);
            csrow[m] = cn;
            hout[(size_t)(((s >> 6) + 1) * 66 + (s & 63) + 1) * 128 + c] = __float2bfloat16(h);
            oframe[(size_t)c * 4096 + s] = fmaxf(h * scv + shv, 0.0f);
        }
    }
}

extern "C" void kernel_launch(void* const* d_in, const int* in_sizes, int n_in,
                              void* d_out, int out_size, void* d_ws, size_t ws_size,
                              hipStream_t stream)
{
    const float* x      = (const float*)d_in[0];
    const float* w_conv = (const float*)d_in[1];
    const float* b_conv = (const float*)d_in[2];
    const float* gamma  = (const float*)d_in[3];
    const float* beta   = (const float*)d_in[4];
    const float* rmean  = (const float*)d_in[5];
    const float* rvar   = (const float*)d_in[6];
    float* out = (float*)d_out;

    // workspace layout (bytes)
    //   Wt      @ 0          : 9*512*256*2    = 2,359,296
    //   x_pad   @ 2359296    : 32*66*66*128*2 = 35,684,352
    //   h_pad   @ 38043648   : 32*66*66*128*2 = 35,684,352   (slot b*8+t = h after step t)
    //   c_state @ 73728000   : 128*16384*4    = 8,388,608    ([c][m]; written before read)
    //   total 82,116,608
    if (ws_size < 82116608u) return;

    char* ws = (char*)d_ws;
    __hip_bfloat16* Wt    = (__hip_bfloat16*)(ws);
    __hip_bfloat16* x_pad = (__hip_bfloat16*)(ws + 2359296);
    __hip_bfloat16* h_pad = (__hip_bfloat16*)(ws + 38043648);
    float* c_state        = (float*)(ws + 73728000);

    wt_kernel<<<4608, 256, 0, stream>>>(w_conv, Wt);
    xpose_kernel<<<2048, 256, 0, stream>>>(x, x_pad);
    border_kernel<<<64, 256, 0, stream>>>(x_pad, h_pad);

    conv_gemm<true><<<512, 256, 0, stream>>>(x_pad, h_pad, Wt, b_conv,
                                             gamma, beta, rmean, rvar, c_state, out, 0);
    for (int t = 1; t < 8; ++t)
        conv_gemm<false><<<512, 256, 0, stream>>>(x_pad, h_pad, Wt, b_conv,
                                                  gamma, beta, rmean, rvar, c_state, out, t);
}

// Round 12
// 635.834 us; speedup vs baseline: 1.0194x; 1.0173x over previous
//
#include <hip/hip_runtime.h>
#include <hip/hip_bf16.h>
#include <math.h>

typedef __attribute__((ext_vector_type(8))) short bf16x8;
typedef __attribute__((ext_vector_type(4))) float f32x4;

#define FRAME_PAD (66*66*128)   // padded NHWC frame elems (557568)

#define GLOAD_LDS16(g, l) \
    __builtin_amdgcn_global_load_lds((const __attribute__((address_space(1))) void*)(g), \
                                     (__attribute__((address_space(3))) void*)(l), 16, 0, 0)

#define WAITV4    asm volatile("s_waitcnt vmcnt(4)" ::: "memory")
#define WAITV0    asm volatile("s_waitcnt vmcnt(0)" ::: "memory")
#define WAITLGKM0 asm volatile("s_waitcnt lgkmcnt(0)" ::: "memory")
#define SBAR      __builtin_amdgcn_s_barrier()

// raw 16B global loads -- volatile asm: cannot be sunk past the fences, no
// compiler-inserted waits (our explicit vmcnt ledger owns completion).
#define GLW16(dst, ptr)  asm volatile("global_load_dwordx4 %0, %1, off"           : "=v"(dst) : "v"(ptr) : "memory")
#define GLW16O(dst, ptr) asm volatile("global_load_dwordx4 %0, %1, off offset:64" : "=v"(dst) : "v"(ptr) : "memory")

__device__ __forceinline__ float sigmoidf_(float x) { return 1.0f / (1.0f + __expf(-x)); }
__device__ __forceinline__ float tanhf_(float x) {
    x = fminf(fmaxf(x, -15.0f), 15.0f);
    float e = __expf(2.0f * x);
    return (e - 1.0f) / (e + 1.0f);
}
__device__ __forceinline__ float b2f_(short u) {
    unsigned int v = ((unsigned int)(unsigned short)u) << 16;
    return __builtin_bit_cast(float, v);
}
__device__ __forceinline__ short f2b_(float f) {
    __hip_bfloat16 hb = __float2bfloat16(f);
    return *reinterpret_cast<short*>(&hb);
}

// ---------- weights: W[oc][ic][tap] f32 -> Wt[tap][n'][ic] bf16, n' = c*4 + gate ----------
__global__ void wt_kernel(const float* __restrict__ w, __hip_bfloat16* __restrict__ wt)
{
    int idx = blockIdx.x * 256 + threadIdx.x;       // tap*131072 + n*256 + ic
    if (idx >= 9 * 512 * 256) return;
    int ic  = idx & 255;
    int n   = (idx >> 8) & 511;
    int tap = idx >> 17;
    int c = n >> 2, g = n & 3;                       // gate 0:i 1:f 2:o 3:g
    int oc = g * 128 + c;
    wt[idx] = __float2bfloat16(w[((size_t)oc * 256 + (size_t)ic) * 9 + tap]);
}

// ---------- zero the pad borders of all x and h frames ----------
__global__ void border_kernel(__hip_bfloat16* __restrict__ x_pad,
                              __hip_bfloat16* __restrict__ h_pad)
{
    const int fr = blockIdx.x;                        // 0..31 x, 32..63 h
    __hip_bfloat16* base = (fr < 32) ? x_pad + (size_t)fr * FRAME_PAD
                                     : h_pad + (size_t)(fr - 32) * FRAME_PAD;
    bf16x8 z = {};
    for (int u = threadIdx.x; u < 2112; u += 256) {
        int half = (u >= 1056) ? 1 : 0;
        int v = u - half * 1056;
        *(bf16x8*)(base + (size_t)(half * 65 * 66) * 128 + (size_t)v * 8) = z;
    }
    for (int u = threadIdx.x; u < 2048; u += 256) {
        int yy = 1 + (u >> 5);
        int r = u & 31;
        int side = r >> 4, c16 = r & 15;
        *(bf16x8*)(base + (size_t)(yy * 66 + side * 65) * 128 + (size_t)c16 * 8) = z;
    }
}

// ---------- x: NCHW f32 -> padded NHWC bf16 (vectorized, LDS stride-129 transpose) ----------
__global__ void xpose_kernel(const float* __restrict__ x, __hip_bfloat16* __restrict__ x_pad)
{
    __shared__ float tile[64][129];                  // [x][c]
    const int f = blockIdx.x >> 6;
    const int y = blockIdx.x & 63;
    const int tid = threadIdx.x;
    const float* src = x + (size_t)f * 524288 + (size_t)y * 64;
    #pragma unroll
    for (int it = 0; it < 8; ++it) {
        int c  = it * 16 + (tid >> 4);
        int xq = tid & 15;
        float4 v = *(const float4*)(src + (size_t)c * 4096 + xq * 4);
        tile[xq * 4 + 0][c] = v.x;
        tile[xq * 4 + 1][c] = v.y;
        tile[xq * 4 + 2][c] = v.z;
        tile[xq * 4 + 3][c] = v.w;
    }
    __syncthreads();
    __hip_bfloat16* dst = x_pad + (size_t)f * FRAME_PAD + (size_t)((y + 1) * 66 + 1) * 128;
    const int g = tid & 15;
    #pragma unroll
    for (int it = 0; it < 4; ++it) {
        int xr = it * 16 + (tid >> 4);
        bf16x8 o;
        #pragma unroll
        for (int e = 0; e < 8; ++e) o[e] = f2b_(tile[xr][g * 8 + e]);
        *(bf16x8*)(dst + (size_t)xr * 128 + g * 8) = o;
    }
}

// ---------- fused conv-GEMM + LSTM + BN/ReLU; W via asm loads L2 -> pinned registers ----------
// R10/R11 failed because the compiler SANK the plain C++ W-loads (read-only memory) to
// their uses, defeating the prefetch (VGPR=104 proved W never resident). asm volatile
// global_load_dwordx4 pins issue placement; our vmcnt ledger owns completion:
// per-thread FIFO [A(kt):4][W(kt):8][A(kt+1):4] -> WAITV4 retires A(kt)+W(kt) exactly.
#define MF(d, wreg, sreg) d = __builtin_amdgcn_mfma_f32_16x16x32_bf16(wreg, sreg, d, 0, 0, 0)

#define LOADW(SET, ktv) do {                                             \
    int tap_, icq_;                                                      \
    if (T0) { tap_ = (ktv) >> 1; icq_ = ((ktv) & 1) * 64; }              \
    else    { tap_ = (ktv) >> 2; icq_ = ((ktv) & 3) * 64; }              \
    const __hip_bfloat16* p_ = wlane + (size_t)tap_ * 131072 + icq_;     \
    GLW16(SET##0, p_);          GLW16O(SET##4, p_);                      \
    GLW16(SET##1, p_ + 4096);   GLW16O(SET##5, p_ + 4096);               \
    GLW16(SET##2, p_ + 8192);   GLW16O(SET##6, p_ + 8192);               \
    GLW16(SET##3, p_ + 12288);  GLW16O(SET##7, p_ + 12288);              \
} while (0)

#define ITER(Sb, WU, WL, ktv) do {                                       \
    if ((ktv) < KT - 1) { WAITV4; } else { WAITV0; }                     \
    SBAR;                                                                \
    if ((ktv) < KT - 1) LOADW(WL, (ktv) + 1);                            \
    bf16x8 s00 = *(const bf16x8*)((Sb) + sOff0 + 0 * 1024);              \
    bf16x8 s01 = *(const bf16x8*)((Sb) + sOff0 + 1 * 1024);              \
    bf16x8 s02 = *(const bf16x8*)((Sb) + sOff0 + 2 * 1024);              \
    bf16x8 s03 = *(const bf16x8*)((Sb) + sOff0 + 3 * 1024);              \
    bf16x8 s10 = *(const bf16x8*)((Sb) + sOff1 + 0 * 1024);              \
    bf16x8 s11 = *(const bf16x8*)((Sb) + sOff1 + 1 * 1024);              \
    bf16x8 s12 = *(const bf16x8*)((Sb) + sOff1 + 2 * 1024);              \
    bf16x8 s13 = *(const bf16x8*)((Sb) + sOff1 + 3 * 1024);              \
    __builtin_amdgcn_s_setprio(1);                                       \
    MF(acc[0][0], WU##0, s00); MF(acc[0][1], WU##0, s01);                \
    MF(acc[0][2], WU##0, s02); MF(acc[0][3], WU##0, s03);                \
    MF(acc[1][0], WU##1, s00); MF(acc[1][1], WU##1, s01);                \
    MF(acc[1][2], WU##1, s02); MF(acc[1][3], WU##1, s03);                \
    MF(acc[2][0], WU##2, s00); MF(acc[2][1], WU##2, s01);                \
    MF(acc[2][2], WU##2, s02); MF(acc[2][3], WU##2, s03);                \
    MF(acc[3][0], WU##3, s00); MF(acc[3][1], WU##3, s01);                \
    MF(acc[3][2], WU##3, s02); MF(acc[3][3], WU##3, s03);                \
    __builtin_amdgcn_s_setprio(0);                                       \
    WAITLGKM0;                                                           \
    __builtin_amdgcn_sched_barrier(0);                                   \
    SBAR;                                                                \
    if ((ktv) < KT - 2) STAGE_A(Sb, (ktv) + 2);                          \
    __builtin_amdgcn_s_setprio(1);                                       \
    MF(acc[0][0], WU##4, s10); MF(acc[0][1], WU##4, s11);                \
    MF(acc[0][2], WU##4, s12); MF(acc[0][3], WU##4, s13);                \
    MF(acc[1][0], WU##5, s10); MF(acc[1][1], WU##5, s11);                \
    MF(acc[1][2], WU##5, s12); MF(acc[1][3], WU##5, s13);                \
    MF(acc[2][0], WU##6, s10); MF(acc[2][1], WU##6, s11);                \
    MF(acc[2][2], WU##6, s12); MF(acc[2][3], WU##6, s13);                \
    MF(acc[3][0], WU##7, s10); MF(acc[3][1], WU##7, s11);                \
    MF(acc[3][2], WU##7, s12); MF(acc[3][3], WU##7, s13);                \
    __builtin_amdgcn_s_setprio(0);                                       \
} while (0)

template<bool T0>
__global__ __launch_bounds__(256, 2)
void conv_gemm(const __hip_bfloat16* __restrict__ x_pad,
               const __hip_bfloat16* __restrict__ h_pad,
               const __hip_bfloat16* __restrict__ wt,
               const float* __restrict__ bias,
               const float* __restrict__ gamma, const float* __restrict__ beta,
               const float* __restrict__ rmean, const float* __restrict__ rvar,
               float* __restrict__ c_state, float* __restrict__ out, int t)
{
    __shared__ alignas(16) __hip_bfloat16 S_s[2][128 * 64];   // spatial dbuf, 2x16KB
    const int tid  = threadIdx.x;
    const int wv   = tid >> 6;
    const int lane = tid & 63;
    const int KT   = T0 ? 18 : 36;

    // XCD-chunked remap: each XCD owns 64 consecutive tiles (16 m-panels x 4 n-blocks).
    const int F    = blockIdx.x;                 // 512 blocks
    const int tile = (F >> 3) + (F & 7) * 64;
    const int n0   = (tile & 3) * 128;
    const int mblk = tile >> 2;                  // 0..127
    const int b    = mblk >> 5;
    const int y0   = (mblk & 31) * 2;
    const int m0   = mblk * 128;

    const __hip_bfloat16* xf = x_pad + (size_t)(b * 8 + t) * FRAME_PAD;
    const __hip_bfloat16* hf = T0 ? xf
                                  : h_pad + (size_t)(b * 8 + t - 1) * FRAME_PAD;

    // A staging offsets (source pre-swizzled: q_src = q ^ (row&7), involution)
    int aOff[4];
    #pragma unroll
    for (int j = 0; j < 4; ++j) {
        int sid = j * 256 + tid;
        int row = sid >> 3;
        int q   = (sid & 7) ^ (row & 7);
        aOff[j] = ((y0 + (row >> 6)) * 66 + (row & 63)) * 128 + q * 8;
    }

    auto STAGE_A = [&](__hip_bfloat16* Sl, int kt) {
        int tap, icq;
        const __hip_bfloat16* sb;
        if constexpr (T0) { tap = kt >> 1; icq = (kt & 1) * 64; sb = xf + icq; }
        else { tap = kt >> 2; icq = (kt & 3) * 64;
               sb = (icq < 128) ? (xf + icq) : (hf + (icq - 128)); }
        const int dy = tap / 3, dx = tap % 3;
        const __hip_bfloat16* a = sb + (dy * 66 + dx) * 128;
        #pragma unroll
        for (int j = 0; j < 4; ++j)
            GLOAD_LDS16(a + aOff[j], Sl + (size_t)(j * 256 + tid) * 8);
    };

    const int wm = wv >> 1, wn = wv & 1;
    const int fr = lane & 15, fq = lane >> 4;

    // W lane base: row n' = n0 + wn*64 + ri*16 + fr, k = icq + fq*8 (+32 for K-half1)
    const __hip_bfloat16* wlane = wt + (size_t)(n0 + wn * 64 + fr) * 256 + fq * 8;

    // A fragment read offsets (swizzled, lane-constant); K-half1 = XOR 32 elems (64B)
    const int slot = (fq ^ (fr & 7)) * 8;
    const int sOff0 = (wm * 64 + fr) * 64 + slot, sOff1 = sOff0 ^ 32;

    f32x4 acc[4][4] = {};
    bf16x8 wA0, wA1, wA2, wA3, wA4, wA5, wA6, wA7;
    bf16x8 wB0, wB1, wB2, wB3, wB4, wB5, wB6, wB7;

    STAGE_A(S_s[0], 0);                          // FIFO: [A0:4]
    LOADW(wA, 0);                                // [A0:4, W0:8]
    STAGE_A(S_s[1], 1);                          // [A0:4, W0:8, A1:4]
    #pragma unroll 1
    for (int kt = 0; kt < KT; kt += 2) {
        ITER(S_s[0], wA, wB, kt);
        ITER(S_s[1], wB, wA, kt + 1);
    }

    // ---------- fused LSTM gates + BN(eval)+ReLU output epilogue ----------
    const int c0    = (n0 >> 2) + wn * 16;
    const int mcol0 = m0 + wm * 64 + fr;
    __hip_bfloat16* hout = (__hip_bfloat16*)h_pad + (size_t)(b * 8 + t) * FRAME_PAD;
    float* oframe = out + (size_t)(b * 8 + t) * 524288;
    #pragma unroll
    for (int ri = 0; ri < 4; ++ri) {
        const int c = c0 + ri * 4 + fq;
        const float bi  = bias[c];
        const float bfv = bias[128 + c];
        const float bo  = bias[256 + c];
        const float bg  = bias[384 + c];
        const float scv = gamma[c] * rsqrtf(rvar[c] + 1e-5f);
        const float shv = beta[c] - rmean[c] * scv;
        float* csrow = c_state + (size_t)c * 16384;
        #pragma unroll
        for (int ci = 0; ci < 4; ++ci) {
            const int m = mcol0 + ci * 16;
            const int s = m & 4095;
            const float cold = T0 ? 0.0f : csrow[m];
            const float zi = acc[ri][ci][0] + bi;
            const float zf = acc[ri][ci][1] + bfv;
            const float zo = acc[ri][ci][2] + bo;
            const float zg = acc[ri][ci][3] + bg;
            const float cn = sigmoidf_(zf) * cold + sigmoidf_(zi) * tanhf_(zg);
            const float h  = sigmoidf_(zo) * tanhf_(cn);
            csrow[m] = cn;
            hout[(size_t)(((s >> 6) + 1) * 66 + (s & 63) + 1) * 128 + c] = __float2bfloat16(h);
            oframe[(size_t)c * 4096 + s] = fmaxf(h * scv + shv, 0.0f);
        }
    }
}

extern "C" void kernel_launch(void* const* d_in, const int* in_sizes, int n_in,
                              void* d_out, int out_size, void* d_ws, size_t ws_size,
                              hipStream_t stream)
{
    const float* x      = (const float*)d_in[0];
    const float* w_conv = (const float*)d_in[1];
    const float* b_conv = (const float*)d_in[2];
    const float* gamma  = (const float*)d_in[3];
    const float* beta   = (const float*)d_in[4];
    const float* rmean  = (const float*)d_in[5];
    const float* rvar   = (const float*)d_in[6];
    float* out = (float*)d_out;

    // workspace layout (bytes)
    //   Wt      @ 0          : 9*512*256*2    = 2,359,296
    //   x_pad   @ 2359296    : 32*66*66*128*2 = 35,684,352
    //   h_pad   @ 38043648   : 32*66*66*128*2 = 35,684,352   (slot b*8+t = h after step t)
    //   c_state @ 73728000   : 128*16384*4    = 8,388,608    ([c][m]; written before read)
    //   total 82,116,608
    if (ws_size < 82116608u) return;

    char* ws = (char*)d_ws;
    __hip_bfloat16* Wt    = (__hip_bfloat16*)(ws);
    __hip_bfloat16* x_pad = (__hip_bfloat16*)(ws + 2359296);
    __hip_bfloat16* h_pad = (__hip_bfloat16*)(ws + 38043648);
    float* c_state        = (float*)(ws + 73728000);

    wt_kernel<<<4608, 256, 0, stream>>>(w_conv, Wt);
    xpose_kernel<<<2048, 256, 0, stream>>>(x, x_pad);
    border_kernel<<<64, 256, 0, stream>>>(x_pad, h_pad);

    conv_gemm<true><<<512, 256, 0, stream>>>(x_pad, h_pad, Wt, b_conv,
                                             gamma, beta, rmean, rvar, c_state, out, 0);
    for (int t = 1; t < 8; ++t)
        conv_gemm<false><<<512, 256, 0, stream>>>(x_pad, h_pad, Wt, b_conv,
                                                  gamma, beta, rmean, rvar, c_state, out, t);
}

// Round 13
// 352.001 us; speedup vs baseline: 1.8415x; 1.8063x over previous
//
#include <hip/hip_runtime.h>
#include <hip/hip_bf16.h>
#include <math.h>

typedef __attribute__((ext_vector_type(8))) short bf16x8;
typedef __attribute__((ext_vector_type(4))) float f32x4;

#define FRAME_PAD (66*66*128)   // padded NHWC frame elems (557568)

#define GLOAD_LDS16(g, l) \
    __builtin_amdgcn_global_load_lds((const __attribute__((address_space(1))) void*)(g), \
                                     (__attribute__((address_space(3))) void*)(l), 16, 0, 0)

#define WAITV8    asm volatile("s_waitcnt vmcnt(8)" ::: "memory")
#define WAITV0    asm volatile("s_waitcnt vmcnt(0)" ::: "memory")
#define WAITLGKM0 asm volatile("s_waitcnt lgkmcnt(0)" ::: "memory")
#define SBAR      __builtin_amdgcn_s_barrier()

__device__ __forceinline__ float sigmoidf_(float x) { return 1.0f / (1.0f + __expf(-x)); }
__device__ __forceinline__ float tanhf_(float x) {
    x = fminf(fmaxf(x, -15.0f), 15.0f);
    float e = __expf(2.0f * x);
    return (e - 1.0f) / (e + 1.0f);
}
__device__ __forceinline__ float b2f_(short u) {
    unsigned int v = ((unsigned int)(unsigned short)u) << 16;
    return __builtin_bit_cast(float, v);
}
__device__ __forceinline__ short f2b_(float f) {
    __hip_bfloat16 hb = __float2bfloat16(f);
    return *reinterpret_cast<short*>(&hb);
}

// ---------- weights: W[oc][ic][tap] f32 -> Wt[tap][n'][ic] bf16, n' = c*4 + gate ----------
__global__ void wt_kernel(const float* __restrict__ w, __hip_bfloat16* __restrict__ wt)
{
    int idx = blockIdx.x * 256 + threadIdx.x;       // tap*131072 + n*256 + ic
    if (idx >= 9 * 512 * 256) return;
    int ic  = idx & 255;
    int n   = (idx >> 8) & 511;
    int tap = idx >> 17;
    int c = n >> 2, g = n & 3;                       // gate 0:i 1:f 2:o 3:g
    int oc = g * 128 + c;
    wt[idx] = __float2bfloat16(w[((size_t)oc * 256 + (size_t)ic) * 9 + tap]);
}

// ---------- zero the pad borders of all x and h frames ----------
__global__ void border_kernel(__hip_bfloat16* __restrict__ x_pad,
                              __hip_bfloat16* __restrict__ h_pad)
{
    const int fr = blockIdx.x;                        // 0..31 x, 32..63 h
    __hip_bfloat16* base = (fr < 32) ? x_pad + (size_t)fr * FRAME_PAD
                                     : h_pad + (size_t)(fr - 32) * FRAME_PAD;
    bf16x8 z = {};
    for (int u = threadIdx.x; u < 2112; u += 256) {
        int half = (u >= 1056) ? 1 : 0;
        int v = u - half * 1056;
        *(bf16x8*)(base + (size_t)(half * 65 * 66) * 128 + (size_t)v * 8) = z;
    }
    for (int u = threadIdx.x; u < 2048; u += 256) {
        int yy = 1 + (u >> 5);
        int r = u & 31;
        int side = r >> 4, c16 = r & 15;
        *(bf16x8*)(base + (size_t)(yy * 66 + side * 65) * 128 + (size_t)c16 * 8) = z;
    }
}

// ---------- x: NCHW f32 -> padded NHWC bf16 (vectorized, LDS stride-129 transpose) ----------
__global__ void xpose_kernel(const float* __restrict__ x, __hip_bfloat16* __restrict__ x_pad)
{
    __shared__ float tile[64][129];                  // [x][c]
    const int f = blockIdx.x >> 6;
    const int y = blockIdx.x & 63;
    const int tid = threadIdx.x;
    const float* src = x + (size_t)f * 524288 + (size_t)y * 64;
    #pragma unroll
    for (int it = 0; it < 8; ++it) {
        int c  = it * 16 + (tid >> 4);
        int xq = tid & 15;
        float4 v = *(const float4*)(src + (size_t)c * 4096 + xq * 4);
        tile[xq * 4 + 0][c] = v.x;
        tile[xq * 4 + 1][c] = v.y;
        tile[xq * 4 + 2][c] = v.z;
        tile[xq * 4 + 3][c] = v.w;
    }
    __syncthreads();
    __hip_bfloat16* dst = x_pad + (size_t)f * FRAME_PAD + (size_t)((y + 1) * 66 + 1) * 128;
    const int g = tid & 15;
    #pragma unroll
    for (int it = 0; it < 4; ++it) {
        int xr = it * 16 + (tid >> 4);
        bf16x8 o;
        #pragma unroll
        for (int e = 0; e < 8; ++e) o[e] = f2b_(tile[xr][g * 8 + e]);
        *(bf16x8*)(dst + (size_t)xr * 128 + g * 8) = o;
    }
}

// ---------- fused conv-GEMM + LSTM gates + BN/ReLU; R3 ITER rhythm @ 2 blocks/CU ----------
// BEST MEASURED STRUCTURE (R9: conv 46.4us, total 352us). D[n'][m]: n' = c*4+gate
// (512, BN=128), m = spatial (16384, BM=128) -> grid 512, dbuf-2 LDS = 64KB -> 2 blocks
// co-resident per CU; BK=64, 16 frag-reads + 32 MFMA per barrier window, counted vmcnt.
// Bracketing (R1..R12): every phasing/ring/co-residency/operand-placement variant lands
// at or above this; W-from-L2 regs is 2x worse (L2 traffic 64KB/CU/K-tile > LDS floor).
template<bool T0>
__global__ __launch_bounds__(256, 2)
void conv_gemm(const __hip_bfloat16* __restrict__ x_pad,
               const __hip_bfloat16* __restrict__ h_pad,
               const __hip_bfloat16* __restrict__ wt,
               const float* __restrict__ bias,
               const float* __restrict__ gamma, const float* __restrict__ beta,
               const float* __restrict__ rmean, const float* __restrict__ rvar,
               float* __restrict__ c_state, float* __restrict__ out, int t)
{
    __shared__ alignas(16) __hip_bfloat16 S_s[2][128 * 64];   // spatial dbuf, 2x16KB
    __shared__ alignas(16) __hip_bfloat16 W_s[2][128 * 64];   // weight dbuf,  2x16KB
    const int tid  = threadIdx.x;
    const int wv   = tid >> 6;
    const int lane = tid & 63;
    const int KT   = T0 ? 18 : 36;

    // XCD-chunked remap: each XCD owns 64 consecutive tiles (16 m-panels x 4 n-blocks).
    const int F    = blockIdx.x;                 // 512 blocks
    const int tile = (F >> 3) + (F & 7) * 64;
    const int n0   = (tile & 3) * 128;
    const int mblk = tile >> 2;                  // 0..127
    const int b    = mblk >> 5;
    const int y0   = (mblk & 31) * 2;
    const int m0   = mblk * 128;

    const __hip_bfloat16* xf = x_pad + (size_t)(b * 8 + t) * FRAME_PAD;
    const __hip_bfloat16* hf = T0 ? xf
                                  : h_pad + (size_t)(b * 8 + t - 1) * FRAME_PAD;

    // per-thread staging offsets (source pre-swizzled: q_src = q ^ (row&7), involution)
    int aOff[4], bOff[4];
    #pragma unroll
    for (int j = 0; j < 4; ++j) {
        int sid = j * 256 + tid;
        int row = sid >> 3;
        int q   = (sid & 7) ^ (row & 7);
        aOff[j] = ((y0 + (row >> 6)) * 66 + (row & 63)) * 128 + q * 8;
        bOff[j] = (n0 + row) * 256 + q * 8;
    }

    auto STAGE = [&](__hip_bfloat16* Sl, __hip_bfloat16* Wl, int kt) {
        int tap, icq;
        const __hip_bfloat16* sb;
        if constexpr (T0) { tap = kt >> 1; icq = (kt & 1) * 64; sb = xf + icq; }
        else { tap = kt >> 2; icq = (kt & 3) * 64;
               sb = (icq < 128) ? (xf + icq) : (hf + (icq - 128)); }
        const int dy = tap / 3, dx = tap % 3;
        const __hip_bfloat16* a = sb + (dy * 66 + dx) * 128;
        #pragma unroll
        for (int j = 0; j < 4; ++j)
            GLOAD_LDS16(a + aOff[j], Sl + (size_t)(j * 256 + tid) * 8);
        const __hip_bfloat16* bsrc = wt + tap * 131072 + icq;
        #pragma unroll
        for (int j = 0; j < 4; ++j)
            GLOAD_LDS16(bsrc + bOff[j], Wl + (size_t)(j * 256 + tid) * 8);
    };

    // fragment read offsets (swizzled, lane-constant); K-half 1 = XOR 32 elems (64B)
    const int wm = wv >> 1, wn = wv & 1;
    const int fr = lane & 15, fq = lane >> 4;
    const int slot = (fq ^ (fr & 7)) * 8;
    const int sOff0 = (wm * 64 + fr) * 64 + slot, sOff1 = sOff0 ^ 32;
    const int wOff0 = (wn * 64 + fr) * 64 + slot, wOff1 = wOff0 ^ 32;

    f32x4 acc[4][4] = {};

    auto ITER = [&](__hip_bfloat16* Sb, __hip_bfloat16* Wb, int kt) {
        if (kt < KT - 1) { WAITV8; } else { WAITV0; }   // tile kt landed; next in flight
        SBAR;
        bf16x8 w0[4], w1[4], s0[4], s1[4];
        #pragma unroll
        for (int ri = 0; ri < 4; ++ri) {
            w0[ri] = *(const bf16x8*)(Wb + wOff0 + ri * 1024);
            w1[ri] = *(const bf16x8*)(Wb + wOff1 + ri * 1024);
        }
        #pragma unroll
        for (int ci = 0; ci < 4; ++ci) {
            s0[ci] = *(const bf16x8*)(Sb + sOff0 + ci * 1024);
            s1[ci] = *(const bf16x8*)(Sb + sOff1 + ci * 1024);
        }
        __builtin_amdgcn_s_setprio(1);
        #pragma unroll
        for (int ri = 0; ri < 4; ++ri)
            #pragma unroll
            for (int ci = 0; ci < 4; ++ci)
                acc[ri][ci] = __builtin_amdgcn_mfma_f32_16x16x32_bf16(w0[ri], s0[ci], acc[ri][ci], 0, 0, 0);
        __builtin_amdgcn_s_setprio(0);
        WAITLGKM0;                               // all 16 reads hardware-complete
        __builtin_amdgcn_sched_barrier(0);       // rule 18: pin the boundary
        SBAR;                                    // all waves done reading this buffer
        if (kt < KT - 2) STAGE(Sb, Wb, kt + 2);  // overwrite now safe; loads fly ahead
        __builtin_amdgcn_s_setprio(1);
        #pragma unroll
        for (int ri = 0; ri < 4; ++ri)
            #pragma unroll
            for (int ci = 0; ci < 4; ++ci)
                acc[ri][ci] = __builtin_amdgcn_mfma_f32_16x16x32_bf16(w1[ri], s1[ci], acc[ri][ci], 0, 0, 0);
        __builtin_amdgcn_s_setprio(0);
    };

    STAGE(S_s[0], W_s[0], 0);
    STAGE(S_s[1], W_s[1], 1);                    // 16 loads/thread in flight
    #pragma unroll 1
    for (int kt = 0; kt < KT; kt += 2) {
        ITER(S_s[0], W_s[0], kt);
        ITER(S_s[1], W_s[1], kt + 1);
    }

    // ---------- fused LSTM gates + BN(eval)+ReLU output epilogue ----------
    const int c0    = (n0 >> 2) + wn * 16;
    const int mcol0 = m0 + wm * 64 + fr;
    __hip_bfloat16* hout = (__hip_bfloat16*)h_pad + (size_t)(b * 8 + t) * FRAME_PAD;
    float* oframe = out + (size_t)(b * 8 + t) * 524288;
    #pragma unroll
    for (int ri = 0; ri < 4; ++ri) {
        const int c = c0 + ri * 4 + fq;
        const float bi  = bias[c];
        const float bfv = bias[128 + c];
        const float bo  = bias[256 + c];
        const float bg  = bias[384 + c];
        const float scv = gamma[c] * rsqrtf(rvar[c] + 1e-5f);
        const float shv = beta[c] - rmean[c] * scv;
        float* csrow = c_state + (size_t)c * 16384;
        #pragma unroll
        for (int ci = 0; ci < 4; ++ci) {
            const int m = mcol0 + ci * 16;
            const int s = m & 4095;
            const float cold = T0 ? 0.0f : csrow[m];
            const float zi = acc[ri][ci][0] + bi;
            const float zf = acc[ri][ci][1] + bfv;
            const float zo = acc[ri][ci][2] + bo;
            const float zg = acc[ri][ci][3] + bg;
            const float cn = sigmoidf_(zf) * cold + sigmoidf_(zi) * tanhf_(zg);
            const float h  = sigmoidf_(zo) * tanhf_(cn);
            csrow[m] = cn;
            hout[(size_t)(((s >> 6) + 1) * 66 + (s & 63) + 1) * 128 + c] = __float2bfloat16(h);
            oframe[(size_t)c * 4096 + s] = fmaxf(h * scv + shv, 0.0f);
        }
    }
}

extern "C" void kernel_launch(void* const* d_in, const int* in_sizes, int n_in,
                              void* d_out, int out_size, void* d_ws, size_t ws_size,
                              hipStream_t stream)
{
    const float* x      = (const float*)d_in[0];
    const float* w_conv = (const float*)d_in[1];
    const float* b_conv = (const float*)d_in[2];
    const float* gamma  = (const float*)d_in[3];
    const float* beta   = (const float*)d_in[4];
    const float* rmean  = (const float*)d_in[5];
    const float* rvar   = (const float*)d_in[6];
    float* out = (float*)d_out;

    // workspace layout (bytes)
    //   Wt      @ 0          : 9*512*256*2    = 2,359,296
    //   x_pad   @ 2359296    : 32*66*66*128*2 = 35,684,352
    //   h_pad   @ 38043648   : 32*66*66*128*2 = 35,684,352   (slot b*8+t = h after step t)
    //   c_state @ 73728000   : 128*16384*4    = 8,388,608    ([c][m]; written before read)
    //   total 82,116,608
    if (ws_size < 82116608u) return;

    char* ws = (char*)d_ws;
    __hip_bfloat16* Wt    = (__hip_bfloat16*)(ws);
    __hip_bfloat16* x_pad = (__hip_bfloat16*)(ws + 2359296);
    __hip_bfloat16* h_pad = (__hip_bfloat16*)(ws + 38043648);
    float* c_state        = (float*)(ws + 73728000);

    wt_kernel<<<4608, 256, 0, stream>>>(w_conv, Wt);
    xpose_kernel<<<2048, 256, 0, stream>>>(x, x_pad);
    border_kernel<<<64, 256, 0, stream>>>(x_pad, h_pad);

    conv_gemm<true><<<512, 256, 0, stream>>>(x_pad, h_pad, Wt, b_conv,
                                             gamma, beta, rmean, rvar, c_state, out, 0);
    for (int t = 1; t < 8; ++t)
        conv_gemm<false><<<512, 256, 0, stream>>>(x_pad, h_pad, Wt, b_conv,
                                                  gamma, beta, rmean, rvar, c_state, out, t);
}